// Round 14
// baseline (351.473 us; speedup 1.0000x reference)
//
#include <hip/hip_runtime.h>
#include <hip/hip_bf16.h>

#define D_ 768
#define E_ 8
#define H_ 3072
#define N_TOK 4096
#define BM 128
#define BN 128
#define BK 32

typedef _Float16 f16;
typedef f16 f16x8 __attribute__((ext_vector_type(8)));
typedef float f32x4 __attribute__((ext_vector_type(4)));

__device__ __forceinline__ void gld16(const f16* g, f16* l) {
    __builtin_amdgcn_global_load_lds(
        (const __attribute__((address_space(1))) unsigned int*)g,
        (__attribute__((address_space(3))) unsigned int*)l, 16, 0, 0);
}

__device__ __forceinline__ int prefix_off(const int* counts, int e, int* cnt_out) {
    int off = 0, cnt = 0;
#pragma unroll
    for (int q = 0; q < E_; q++) {
        int cq = counts[q];
        if (q < e) off += cq;
        if (q == e) cnt = cq;
    }
    *cnt_out = cnt;
    return off;
}

// swizzle: logical 16B-chunk q of row r stored at physical chunk ((q^(r&3))+((r>>2)&3))&3 within each 64B group
__device__ __forceinline__ int swz_pos(int h, int row) {
    int q = (h >> 3) & 3;
    int p = (((q ^ (row & 3)) + ((row >> 2) & 3)) & 3);
    return (h & ~0x1F) | (p << 3) | (h & 7);
}

// ---------------- combined weight convert+transpose+swizzle ----------------
__global__ __launch_bounds__(256) void cvt_w_both(const float* __restrict__ w1,
                                                  const float* __restrict__ w2,
                                                  f16* __restrict__ w1t,
                                                  f16* __restrict__ w2t) {
    __shared__ f16 t[64][66];
    int z = blockIdx.z;
    const float* src; f16* dst; int R, C, xb, yb;
    int bx = blockIdx.x;
    if (z < E_) {
        src = w1 + (size_t)z * D_ * H_; dst = w1t + (size_t)z * D_ * H_;
        R = D_; C = H_; xb = bx % 48; yb = bx / 48;
    } else {
        src = w2 + (size_t)(z - E_) * H_ * D_; dst = w2t + (size_t)(z - E_) * H_ * D_;
        R = H_; C = D_; xb = bx % 12; yb = bx / 12;
    }
    int r0 = yb * 64, c0 = xb * 64;
    int tid = threadIdx.x;
    {
        int r = tid >> 4;
        int c = (tid & 15) * 4;
#pragma unroll
        for (int i = 0; i < 4; i++) {
            float4 v = *(const float4*)(src + (size_t)(r0 + r + i * 16) * C + (c0 + c));
            t[r + i * 16][c] = (f16)v.x;
            t[r + i * 16][c + 1] = (f16)v.y;
            t[r + i * 16][c + 2] = (f16)v.z;
            t[r + i * 16][c + 3] = (f16)v.w;
        }
    }
    __syncthreads();
    {
        int c = tid >> 3;
        int rr = (tid & 7) * 8;
#pragma unroll
        for (int i = 0; i < 2; i++) {
            int cc = c + i * 32;
            int rowi = c0 + cc;
            f16x8 o;
#pragma unroll
            for (int j = 0; j < 8; j++) o[j] = t[rr + j][cc];
            *(f16x8*)(dst + (size_t)rowi * R + swz_pos(r0 + rr, rowi)) = o;
        }
    }
}

// ---------------- router: coalesced GEMV + LDS-aggregated atomics ----------------
__global__ __launch_bounds__(1024) void router(const float* __restrict__ x,
                                               const float* __restrict__ gw,
                                               const float* __restrict__ gb,
                                               int* __restrict__ counts,
                                               int* __restrict__ list,
                                               float* __restrict__ wslot) {
    __shared__ int lcount[E_];
    __shared__ int lbase[E_];
    __shared__ int te0[64], te1[64], ts0[64], ts1[64];
    __shared__ float tw0[64], tw1[64];

    int tid = threadIdx.x;
    int wv = tid >> 6, lane = tid & 63;
    int s = lane >> 3, eL = lane & 7;
    if (tid < E_) lcount[tid] = 0;
    __syncthreads();

    float biasL = gb[eL];

#pragma unroll 1
    for (int i = 0; i < 4; i++) {
        int lt = wv * 4 + i;
        int tok = blockIdx.x * 64 + lt;
        const float* xr = x + (size_t)tok * D_;
        float a = 0.f;
        const float* gwl = gw + lane;
#pragma unroll 8
        for (int j = 0; j < 96; j++)
            a = fmaf(xr[j * 8 + s], gwl[j * 64], a);
        a += __shfl_xor(a, 8, 64);
        a += __shfl_xor(a, 16, 64);
        a += __shfl_xor(a, 32, 64);
        float lg = a + biasL;
        float le[8];
#pragma unroll
        for (int q = 0; q < 8; q++) le[q] = __shfl(lg, q, 64);
        float v0 = -3.4e38f, v1 = -3.4e38f;
        int i0 = 0, i1 = 0;
#pragma unroll
        for (int q = 0; q < 8; q++) {
            float l = le[q];
            if (l > v0) { v1 = v0; i1 = i0; v0 = l; i0 = q; }
            else if (l > v1) { v1 = l; i1 = q; }
        }
        if (lane == 0) {
            float p1 = expf(v1 - v0);
            float ssum = 1.f + p1;
            int s0 = atomicAdd(&lcount[i0], 1);
            int s1 = atomicAdd(&lcount[i1], 1);
            te0[lt] = i0; ts0[lt] = s0; tw0[lt] = 1.f / ssum;
            te1[lt] = i1; ts1[lt] = s1; tw1[lt] = p1 / ssum;
        }
    }
    __syncthreads();
    if (tid < E_) lbase[tid] = atomicAdd(&counts[tid], lcount[tid]);
    __syncthreads();
    if (tid < 64) {
        int tok = blockIdx.x * 64 + tid;
        int e0 = te0[tid], e1 = te1[tid];
        list[e0 * N_TOK + lbase[e0] + ts0[tid]] = tok * 2;
        list[e1 * N_TOK + lbase[e1] + ts1[tid]] = tok * 2 + 1;
        wslot[tok * 2] = tw0[tid];
        wslot[tok * 2 + 1] = tw1[tid];
    }
}

// ---------------- pack A: gather token rows -> packed swizzled fp16 [8192][D] ----------------
__global__ __launch_bounds__(256) void pack_a(const float* __restrict__ x,
                                              const int* __restrict__ counts,
                                              const int* __restrict__ list,
                                              f16* __restrict__ xg) {
    int wv = threadIdx.x >> 6, lane = threadIdx.x & 63;
    int idx = blockIdx.x * 4 + wv;
    int e = idx >> 12, j = idx & (N_TOK - 1);
    int cnt;
    int off = prefix_off(counts, e, &cnt);
    if (j >= cnt) return;
    int id = list[idx];
    int row = off + j;
    const float* xr = x + (size_t)(id >> 1) * D_;
    f16* dst = xg + (size_t)row * D_;
#pragma unroll
    for (int c = 0; c < 3; c++) {
        int h = lane * 4 + c * 256;
        float4 v = *(const float4*)(xr + h);
        f16 o[4] = {(f16)v.x, (f16)v.y, (f16)v.z, (f16)v.w};
        *(float2*)(dst + swz_pos(h, row)) = *(const float2*)o;
    }
}

// ---------------- GEMM1: h = gelu(xg @ w1 + b1), 128x128x32, gld_lds, XCD-pinned, L2-blocked ----------------
__global__ __launch_bounds__(256, 5) void gemm1(const f16* __restrict__ xg,
                                                const f16* __restrict__ w1t,
                                                const float* __restrict__ b1,
                                                const int* __restrict__ counts,
                                                f16* __restrict__ hbuf) {
    int bid = blockIdx.x;
    int e = bid & 7;
    int r = bid >> 3;
    int xb12 = r % 12;
    int yb = (r / 12) % 32;
    int xh = r / (12 * 32);          // 0..1
    int cnt;
    int off = prefix_off(counts, e, &cnt);
    int rb = yb * BM;
    if (rb >= cnt) return;
    int cb = (xh * 12 + xb12) * BN;

    __shared__ f16 lds[2 * BM * BK];   // A halfs [0,4096), B halfs [4096,8192)  -> 16KB
    char* ldsb = (char*)lds;

    int tid = threadIdx.x;
    int w = tid >> 6, l = tid & 63;

    int arow0 = w * 16 + (l >> 2);
    int arow1 = 64 + arow0;
    int ag0 = off + rb + arow0; if (ag0 > 8191) ag0 = 8191;
    int ag1 = off + rb + arow1; if (ag1 > 8191) ag1 = 8191;
    const f16* ap0 = xg + (size_t)ag0 * D_ + (l & 3) * 8;
    const f16* ap1 = xg + (size_t)ag1 * D_ + (l & 3) * 8;
    const f16* bbase = w1t + (size_t)e * H_ * D_;
    const f16* bp0 = bbase + (size_t)(cb + arow0) * D_ + (l & 3) * 8;
    const f16* bp1 = bbase + (size_t)(cb + arow1) * D_ + (l & 3) * 8;
    f16* la0 = lds + w * 512;
    f16* la1 = lds + 2048 + w * 512;
    f16* lb0 = lds + 4096 + w * 512;
    f16* lb1 = lds + 6144 + w * 512;

    int wr = (w >> 1) * 64, wc = (w & 1) * 64;
    int fr = l & 15, qh = l >> 4;

    int roA[4], roB[4];
#pragma unroll
    for (int m = 0; m < 4; m++) {
        int rA = wr + m * 16 + fr;
        int g = off + rb + rA;
        int pA = (((qh ^ (g & 3)) + ((g >> 2) & 3)) & 3);
        roA[m] = rA * 64 + pA * 16;
        int rB = wc + m * 16 + fr;
        int pB = (((qh ^ (rB & 3)) + ((rB >> 2) & 3)) & 3);
        roB[m] = 8192 + rB * 64 + pB * 16;
    }

    f32x4 acc[4][4] = {};
    const int NT = D_ / BK;  // 24
#pragma unroll 1
    for (int t = 0; t < NT; ++t) {
        int kk = t * BK;
        gld16(ap0 + kk, la0);
        gld16(ap1 + kk, la1);
        gld16(bp0 + kk, lb0);
        gld16(bp1 + kk, lb1);
        __syncthreads();
        f16x8 af[4], bf[4];
#pragma unroll
        for (int m = 0; m < 4; m++) af[m] = *(const f16x8*)(ldsb + roA[m]);
#pragma unroll
        for (int n = 0; n < 4; n++) bf[n] = *(const f16x8*)(ldsb + roB[n]);
#pragma unroll
        for (int m = 0; m < 4; m++)
#pragma unroll
            for (int n = 0; n < 4; n++)
                acc[m][n] = __builtin_amdgcn_mfma_f32_16x16x32_f16(af[m], bf[n], acc[m][n], 0, 0, 0);
        __syncthreads();
    }

#pragma unroll
    for (int n = 0; n < 4; n++) {
        int colg = cb + wc + n * 16 + fr;
        float bias = b1[e * H_ + colg];
#pragma unroll
        for (int m = 0; m < 4; m++) {
#pragma unroll
            for (int r2 = 0; r2 < 4; r2++) {
                int j = rb + wr + m * 16 + qh * 4 + r2;
                if (j < cnt) {
                    float v = acc[m][n][r2] + bias;
                    v = 0.5f * v * (1.f + erff(v * 0.70710678f));
                    int row = off + j;
                    hbuf[(size_t)row * H_ + swz_pos(colg, row)] = (f16)v;
                }
            }
        }
    }
}

// ---------------- GEMM2: y = (hbuf @ w2 + b2) * wslot, scatter-add, XCD-pinned, L2-blocked ----------------
#define KSPLIT 4
#define KCH (H_ / KSPLIT)   // 768
__global__ __launch_bounds__(256, 5) void gemm2(const f16* __restrict__ hbuf,
                                                const f16* __restrict__ w2t,
                                                const float* __restrict__ b2,
                                                const int* __restrict__ counts,
                                                const int* __restrict__ list,
                                                const float* __restrict__ wslot,
                                                float* __restrict__ out) {
    int bid = blockIdx.x;
    int e = bid & 7;
    int r = bid >> 3;
    int cb6 = r % 6;
    int yb = (r / 6) % 32;
    int kz = r / (6 * 32);           // 0..3
    int cnt;
    int off = prefix_off(counts, e, &cnt);
    int rb = yb * BM;
    if (rb >= cnt) return;
    int cb = cb6 * BN;
    int k0 = kz * KCH;

    __shared__ f16 lds[2 * BM * BK];
    char* ldsb = (char*)lds;

    int tid = threadIdx.x;
    int w = tid >> 6, l = tid & 63;

    int arow0 = w * 16 + (l >> 2);
    int arow1 = 64 + arow0;
    int ag0 = off + rb + arow0; if (ag0 > 8191) ag0 = 8191;
    int ag1 = off + rb + arow1; if (ag1 > 8191) ag1 = 8191;
    const f16* ap0 = hbuf + (size_t)ag0 * H_ + k0 + (l & 3) * 8;
    const f16* ap1 = hbuf + (size_t)ag1 * H_ + k0 + (l & 3) * 8;
    const f16* bbase = w2t + (size_t)e * D_ * H_;
    const f16* bp0 = bbase + (size_t)(cb + arow0) * H_ + k0 + (l & 3) * 8;
    const f16* bp1 = bbase + (size_t)(cb + arow1) * H_ + k0 + (l & 3) * 8;
    f16* la0 = lds + w * 512;
    f16* la1 = lds + 2048 + w * 512;
    f16* lb0 = lds + 4096 + w * 512;
    f16* lb1 = lds + 6144 + w * 512;

    int wr = (w >> 1) * 64, wc = (w & 1) * 64;
    int fr = l & 15, qh = l >> 4;

    int roA[4], roB[4];
#pragma unroll
    for (int m = 0; m < 4; m++) {
        int rA = wr + m * 16 + fr;
        int g = off + rb + rA;
        int pA = (((qh ^ (g & 3)) + ((g >> 2) & 3)) & 3);
        roA[m] = rA * 64 + pA * 16;
        int rB = wc + m * 16 + fr;
        int pB = (((qh ^ (rB & 3)) + ((rB >> 2) & 3)) & 3);
        roB[m] = 8192 + rB * 64 + pB * 16;
    }

    f32x4 acc[4][4] = {};
    const int NT = KCH / BK;  // 24
#pragma unroll 1
    for (int t = 0; t < NT; ++t) {
        int kk = t * BK;
        gld16(ap0 + kk, la0);
        gld16(ap1 + kk, la1);
        gld16(bp0 + kk, lb0);
        gld16(bp1 + kk, lb1);
        __syncthreads();
        f16x8 af[4], bf[4];
#pragma unroll
        for (int m = 0; m < 4; m++) af[m] = *(const f16x8*)(ldsb + roA[m]);
#pragma unroll
        for (int n = 0; n < 4; n++) bf[n] = *(const f16x8*)(ldsb + roB[n]);
#pragma unroll
        for (int m = 0; m < 4; m++)
#pragma unroll
            for (int n = 0; n < 4; n++)
                acc[m][n] = __builtin_amdgcn_mfma_f32_16x16x32_f16(af[m], bf[n], acc[m][n], 0, 0, 0);
        __syncthreads();
    }

#pragma unroll
    for (int n = 0; n < 4; n++) {
        int colg = cb + wc + n * 16 + fr;
        float bias = (kz == 0) ? b2[e * D_ + colg] : 0.f;
#pragma unroll
        for (int m = 0; m < 4; m++) {
#pragma unroll
            for (int r2 = 0; r2 < 4; r2++) {
                int j = rb + wr + m * 16 + qh * 4 + r2;
                if (j < cnt) {
                    int id = list[e * N_TOK + j];
                    float wgt = wslot[id];
                    float v = (acc[m][n][r2] + bias) * wgt;
                    atomicAdd(&out[(size_t)(id >> 1) * D_ + colg], v);
                }
            }
        }
    }
}

extern "C" void kernel_launch(void* const* d_in, const int* in_sizes, int n_in,
                              void* d_out, int out_size, void* d_ws, size_t ws_size,
                              hipStream_t stream) {
    const float* x = (const float*)d_in[0];
    const float* gate_w = (const float*)d_in[1];
    const float* gate_b = (const float*)d_in[2];
    const float* w1 = (const float*)d_in[3];
    const float* b1 = (const float*)d_in[4];
    const float* w2 = (const float*)d_in[5];
    const float* b2 = (const float*)d_in[6];
    float* out = (float*)d_out;

    char* ws = (char*)d_ws;
    int* counts = (int*)ws;                           // 32 B
    int* list = (int*)(ws + 1024);                    // 131072 B
    float* wslot = (float*)(ws + 132096);             // 32768 B
    f16* xg = (f16*)(ws + 196608);                    // 12582912 B
    f16* w1t = (f16*)(ws + 12779520);                 // 37748736 B
    f16* w2t = (f16*)(ws + 50528256);                 // 37748736 B
    f16* hbuf = (f16*)(ws + 88276992);                // 50331648 B

    hipMemsetAsync(counts, 0, 256, stream);
    hipMemsetAsync(out, 0, (size_t)out_size * sizeof(float), stream);

    router<<<64, 1024, 0, stream>>>(x, gate_w, gate_b, counts, list, wslot);
    pack_a<<<E_ * N_TOK / 4, 256, 0, stream>>>(x, counts, list, xg);
    cvt_w_both<<<dim3(576, 1, 16), 256, 0, stream>>>(w1, w2, w1t, w2t);
    gemm1<<<E_ * 2 * 32 * 12, 256, 0, stream>>>(xg, w1t, b1, counts, hbuf);
    gemm2<<<E_ * KSPLIT * 32 * 6, 256, 0, stream>>>(hbuf, w2t, b2, counts, list, wslot, out);
}

// Round 16
// 270.837 us; speedup vs baseline: 1.2977x; 1.2977x over previous
//
#include <hip/hip_runtime.h>
#include <hip/hip_bf16.h>

#define D_ 768
#define E_ 8
#define H_ 3072
#define N_TOK 4096
#define BT 64
#define BK 64

typedef _Float16 f16;
typedef f16 f16x8 __attribute__((ext_vector_type(8)));
typedef float f32x4 __attribute__((ext_vector_type(4)));

__device__ __forceinline__ void gld16(const f16* g, f16* l) {
    __builtin_amdgcn_global_load_lds(
        (const __attribute__((address_space(1))) unsigned int*)g,
        (__attribute__((address_space(3))) unsigned int*)l, 16, 0, 0);
}

__device__ __forceinline__ int prefix_off(const int* counts, int e, int* cnt_out) {
    int off = 0, cnt = 0;
#pragma unroll
    for (int q = 0; q < E_; q++) {
        int cq = counts[q];
        if (q < e) off += cq;
        if (q == e) cnt = cq;
    }
    *cnt_out = cnt;
    return off;
}

// ---------------- combined weight convert+transpose+swizzle (w1 & w2 in one launch) ----------------
// fp32 [R][C] -> fp16 [C][R], output row swizzled in 16B chunks: chunk k at k^(row&7).
__global__ __launch_bounds__(256) void cvt_w_both(const float* __restrict__ w1,
                                                  const float* __restrict__ w2,
                                                  f16* __restrict__ w1t,
                                                  f16* __restrict__ w2t) {
    __shared__ f16 t[64][66];
    int z = blockIdx.z;
    const float* src; f16* dst; int R, C, xb, yb;
    int bx = blockIdx.x;
    if (z < E_) {
        src = w1 + (size_t)z * D_ * H_; dst = w1t + (size_t)z * D_ * H_;
        R = D_; C = H_; xb = bx % 48; yb = bx / 48;
    } else {
        src = w2 + (size_t)(z - E_) * H_ * D_; dst = w2t + (size_t)(z - E_) * H_ * D_;
        R = H_; C = D_; xb = bx % 12; yb = bx / 12;
    }
    int r0 = yb * 64, c0 = xb * 64;
    int tid = threadIdx.x;
    {
        int r = tid >> 4;
        int c = (tid & 15) * 4;
#pragma unroll
        for (int i = 0; i < 4; i++) {
            float4 v = *(const float4*)(src + (size_t)(r0 + r + i * 16) * C + (c0 + c));
            t[r + i * 16][c] = (f16)v.x;
            t[r + i * 16][c + 1] = (f16)v.y;
            t[r + i * 16][c + 2] = (f16)v.z;
            t[r + i * 16][c + 3] = (f16)v.w;
        }
    }
    __syncthreads();
    {
        int c = tid >> 3;
        int rr = (tid & 7) * 8;
        int ch = rr >> 3;
#pragma unroll
        for (int i = 0; i < 2; i++) {
            int cc = c + i * 32;
            int rowi = c0 + cc;
            f16x8 o;
#pragma unroll
            for (int j = 0; j < 8; j++) o[j] = t[rr + j][cc];
            *(f16x8*)(dst + (size_t)rowi * R + r0 + (((ch ^ rowi) & 7) << 3)) = o;
        }
    }
}

// ---------------- router: coalesced GEMV + LDS-aggregated atomics ----------------
__global__ __launch_bounds__(1024) void router(const float* __restrict__ x,
                                               const float* __restrict__ gw,
                                               const float* __restrict__ gb,
                                               int* __restrict__ counts,
                                               int* __restrict__ list,
                                               float* __restrict__ wslot) {
    __shared__ int lcount[E_];
    __shared__ int lbase[E_];
    __shared__ int te0[64], te1[64], ts0[64], ts1[64];
    __shared__ float tw0[64], tw1[64];

    int tid = threadIdx.x;
    int wv = tid >> 6, lane = tid & 63;
    int s = lane >> 3, eL = lane & 7;
    if (tid < E_) lcount[tid] = 0;
    __syncthreads();

    float biasL = gb[eL];

#pragma unroll 1
    for (int i = 0; i < 4; i++) {
        int lt = wv * 4 + i;
        int tok = blockIdx.x * 64 + lt;
        const float* xr = x + (size_t)tok * D_;
        float a = 0.f;
        const float* gwl = gw + lane;
#pragma unroll 8
        for (int j = 0; j < 96; j++)
            a = fmaf(xr[j * 8 + s], gwl[j * 64], a);
        a += __shfl_xor(a, 8, 64);
        a += __shfl_xor(a, 16, 64);
        a += __shfl_xor(a, 32, 64);
        float lg = a + biasL;
        float le[8];
#pragma unroll
        for (int q = 0; q < 8; q++) le[q] = __shfl(lg, q, 64);
        float v0 = -3.4e38f, v1 = -3.4e38f;
        int i0 = 0, i1 = 0;
#pragma unroll
        for (int q = 0; q < 8; q++) {
            float l = le[q];
            if (l > v0) { v1 = v0; i1 = i0; v0 = l; i0 = q; }
            else if (l > v1) { v1 = l; i1 = q; }
        }
        if (lane == 0) {
            float p1 = expf(v1 - v0);
            float ssum = 1.f + p1;
            int s0 = atomicAdd(&lcount[i0], 1);
            int s1 = atomicAdd(&lcount[i1], 1);
            te0[lt] = i0; ts0[lt] = s0; tw0[lt] = 1.f / ssum;
            te1[lt] = i1; ts1[lt] = s1; tw1[lt] = p1 / ssum;
        }
    }
    __syncthreads();
    if (tid < E_) lbase[tid] = atomicAdd(&counts[tid], lcount[tid]);
    __syncthreads();
    if (tid < 64) {
        int tok = blockIdx.x * 64 + tid;
        int e0 = te0[tid], e1 = te1[tid];
        list[e0 * N_TOK + lbase[e0] + ts0[tid]] = tok * 2;
        list[e1 * N_TOK + lbase[e1] + ts1[tid]] = tok * 2 + 1;
        wslot[tok * 2] = tw0[tid];
        wslot[tok * 2 + 1] = tw1[tid];
    }
}

// ---------------- pack A: gather token rows -> packed swizzled fp16 [8192][D] ----------------
__global__ __launch_bounds__(256) void pack_a(const float* __restrict__ x,
                                              const int* __restrict__ counts,
                                              const int* __restrict__ list,
                                              f16* __restrict__ xg) {
    int wv = threadIdx.x >> 6, lane = threadIdx.x & 63;
    int idx = blockIdx.x * 4 + wv;
    int e = idx >> 12, j = idx & (N_TOK - 1);
    int cnt;
    int off = prefix_off(counts, e, &cnt);
    if (j >= cnt) return;
    int id = list[idx];
    int row = off + j;
    const float* xr = x + (size_t)(id >> 1) * D_;
    f16* dst = xg + (size_t)row * D_;
    int r7 = row & 7;
#pragma unroll
    for (int c = 0; c < 3; c++) {
        int h = lane * 4 + c * 256;
        float4 v = *(const float4*)(xr + h);
        f16 o[4] = {(f16)v.x, (f16)v.y, (f16)v.z, (f16)v.w};
        int hs = (h & ~0x3F) | ((((h >> 3) ^ r7) & 7) << 3) | (h & 7);
        *(float2*)(dst + hs) = *(const float2*)o;
    }
}

// ---------------- GEMM1: h = gelu(xg @ w1 + b1), 64x64, gld_lds, XCD-pinned, L2-blocked ----------------
__global__ __launch_bounds__(256, 8) void gemm1(const f16* __restrict__ xg,
                                                const f16* __restrict__ w1t,
                                                const float* __restrict__ b1,
                                                const int* __restrict__ counts,
                                                f16* __restrict__ hbuf) {
    int bid = blockIdx.x;
    int e = bid & 7;
    int r = bid >> 3;
    int xb24 = r % 24;
    int yb = (r / 24) % 64;
    int xh = r / (24 * 64);
    int cnt;
    int off = prefix_off(counts, e, &cnt);
    int rb = yb * BT;
    if (rb >= cnt) return;
    int cb = (xh * 24 + xb24) * BT;

    __shared__ f16 lds[2 * BT * BK];
    char* ldsb = (char*)lds;

    int tid = threadIdx.x;
    int wv = tid >> 6, lane = tid & 63;
    int lr = lane >> 3, lc = lane & 7;

    int r0l = wv * 8 + lr;
    int r1l = 32 + wv * 8 + lr;
    int ag0 = off + rb + r0l; if (ag0 > 8191) ag0 = 8191;
    int ag1 = off + rb + r1l; if (ag1 > 8191) ag1 = 8191;
    const f16* ap0 = xg + (size_t)ag0 * D_ + lc * 8;
    const f16* ap1 = xg + (size_t)ag1 * D_ + lc * 8;
    const f16* wb = w1t + (size_t)e * H_ * D_;
    const f16* bp0 = wb + (size_t)(cb + r0l) * D_ + lc * 8;
    const f16* bp1 = wb + (size_t)(cb + r1l) * D_ + lc * 8;
    f16* la0 = lds + wv * 512;
    f16* la1 = lds + 2048 + wv * 512;
    f16* lb0 = lds + 4096 + wv * 512;
    f16* lb1 = lds + 6144 + wv * 512;

    int wr = (wv >> 1) * 32, wc = (wv & 1) * 32;
    int fr = lane & 15, qh = lane >> 4;
    int koff = (off + rb) & 7;

    int roA[2][2], roB[2][2];
#pragma unroll
    for (int m = 0; m < 2; m++)
#pragma unroll
        for (int ks = 0; ks < 2; ks++) {
            int row = wr + m * 16 + fr;
            roA[m][ks] = row * 128 + ((((ks * 4 + qh) ^ (koff + row)) & 7) << 4);
            int rwb = wc + m * 16 + fr;
            roB[m][ks] = 8192 + rwb * 128 + ((((ks * 4 + qh) ^ rwb) & 7) << 4);
        }

    f32x4 acc[2][2] = {};
    const int NT = D_ / BK;  // 12
#pragma unroll 1
    for (int t = 0; t < NT; ++t) {
        int kk = t * BK;
        gld16(ap0 + kk, la0);
        gld16(ap1 + kk, la1);
        gld16(bp0 + kk, lb0);
        gld16(bp1 + kk, lb1);
        __syncthreads();
#pragma unroll
        for (int ks = 0; ks < 2; ks++) {
            f16x8 a0 = *(const f16x8*)(ldsb + roA[0][ks]);
            f16x8 a1 = *(const f16x8*)(ldsb + roA[1][ks]);
            f16x8 b0 = *(const f16x8*)(ldsb + roB[0][ks]);
            f16x8 b1v = *(const f16x8*)(ldsb + roB[1][ks]);
            acc[0][0] = __builtin_amdgcn_mfma_f32_16x16x32_f16(a0, b0, acc[0][0], 0, 0, 0);
            acc[0][1] = __builtin_amdgcn_mfma_f32_16x16x32_f16(a0, b1v, acc[0][1], 0, 0, 0);
            acc[1][0] = __builtin_amdgcn_mfma_f32_16x16x32_f16(a1, b0, acc[1][0], 0, 0, 0);
            acc[1][1] = __builtin_amdgcn_mfma_f32_16x16x32_f16(a1, b1v, acc[1][1], 0, 0, 0);
        }
        __syncthreads();
    }

#pragma unroll
    for (int n = 0; n < 2; n++) {
        int colg = cb + wc + n * 16 + fr;
        float bias = b1[e * H_ + colg];
#pragma unroll
        for (int m = 0; m < 2; m++) {
#pragma unroll
            for (int r2 = 0; r2 < 4; r2++) {
                int j = rb + wr + m * 16 + qh * 4 + r2;
                if (j < cnt) {
                    float v = acc[m][n][r2] + bias;
                    v = 0.5f * v * (1.f + erff(v * 0.70710678f));
                    int row = off + j;
                    int hs = (colg & ~0x3F) | ((((colg >> 3) ^ row) & 7) << 3) | (colg & 7);
                    hbuf[(size_t)row * H_ + hs] = (f16)v;
                }
            }
        }
    }
}

// ---------------- GEMM2: pipelined 128x128x64, 8 waves, counted-vmcnt dbuf ----------------
// Staging fixed: wave-uniform LDS bases (rule m104) — instruction j of wave w covers
// chunks c = j*512 + w*64 + lane, LDS base = (j*512 + w*64)*16 bytes (uniform per wave).
#define KSPLIT 2
#define KCH (H_ / KSPLIT)   // 1536
#define G2BM 128
#define G2BN 128
#define G2BK 64
__global__ __launch_bounds__(512, 4) void gemm2(const f16* __restrict__ hbuf,
                                                const f16* __restrict__ w2t,
                                                const float* __restrict__ b2,
                                                const int* __restrict__ counts,
                                                const int* __restrict__ list,
                                                const float* __restrict__ wslot,
                                                float* __restrict__ out) {
    int bid = blockIdx.x;
    int e = bid & 7;                 // expert -> XCD
    int r = bid >> 3;
    int cb6 = r % 6;                 // fastest
    int yb = (r / 6) % 32;
    int kz = r / (6 * 32);           // slowest (L2: 2.35MB B-half resident)
    int cnt;
    int off = prefix_off(counts, e, &cnt);
    int rb = yb * G2BM;
    if (rb >= cnt) return;
    int cb = cb6 * G2BN;
    int k0 = kz * KCH;

    __shared__ f16 lds[2 * (G2BM + G2BN) * G2BK];   // 64 KB: per buf, A @0 (16KB), B @16KB
    char* ldsb = (char*)lds;

    int tid = threadIdx.x;
    int w = tid >> 6, l = tid & 63;
    int fr = l & 15, qh = l >> 4;
    int wm = w >> 2, wn = w & 3;     // 2 M-waves x 4 N-waves

    // per-wave staging: j=0..1 for A (1024 chunks), j=0..1 for B
    const f16* gpA[2]; const f16* gpB[2];
    f16* lbA[2]; f16* lbB[2];
#pragma unroll
    for (int j = 0; j < 2; j++) {
        int c = j * 512 + w * 64 + l;        // chunk 0..1023
        int rowi = c >> 3, q = c & 7;
        int ag = off + rb + rowi; if (ag > 8191) ag = 8191;
        gpA[j] = hbuf + (size_t)ag * H_ + k0 + q * 8;
        lbA[j] = lds + j * 4096 + w * 512;   // wave-uniform (halfs)
        gpB[j] = w2t + (size_t)e * D_ * H_ + (size_t)(cb + rowi) * H_ + k0 + q * 8;
        lbB[j] = lds + 8192 + j * 4096 + w * 512;
    }

    // ds_read offsets (XOR-8 row format; A swizzle param = global packed row; B local row, cb%8==0)
    int roA[4][2], roB[2][2];
#pragma unroll
    for (int m = 0; m < 4; m++)
#pragma unroll
        for (int ks = 0; ks < 2; ks++) {
            int rA = wm * 64 + m * 16 + fr;
            int g = off + rb + rA;
            roA[m][ks] = rA * 128 + ((((ks * 4 + qh) ^ g) & 7) << 4);
        }
#pragma unroll
    for (int n = 0; n < 2; n++)
#pragma unroll
        for (int ks = 0; ks < 2; ks++) {
            int rB = wn * 32 + n * 16 + fr;
            roB[n][ks] = 16384 + rB * 128 + ((((ks * 4 + qh) ^ rB) & 7) << 4);
        }

#define G2STAGE(t, buf) do {                                   \
    int kko = (t) * G2BK;                                      \
    gld16(gpA[0] + kko, lbA[0] + (buf) * 16384);               \
    gld16(gpA[1] + kko, lbA[1] + (buf) * 16384);               \
    gld16(gpB[0] + kko, lbB[0] + (buf) * 16384);               \
    gld16(gpB[1] + kko, lbB[1] + (buf) * 16384);               \
} while (0)

    f32x4 acc[4][2] = {};
    const int NT = KCH / G2BK;   // 24

    G2STAGE(0, 0);
    G2STAGE(1, 1);

#pragma unroll 1
    for (int t = 0; t < NT; ++t) {
        if (t + 1 < NT) asm volatile("s_waitcnt vmcnt(4)" ::: "memory");
        else            asm volatile("s_waitcnt vmcnt(0)" ::: "memory");
        __syncthreads();
        int bo = (t & 1) * 32768;
        f16x8 af[4], bf[2];
#pragma unroll
        for (int ks = 0; ks < 2; ks++) {
#pragma unroll
            for (int m = 0; m < 4; m++) af[m] = *(const f16x8*)(ldsb + bo + roA[m][ks]);
#pragma unroll
            for (int n = 0; n < 2; n++) bf[n] = *(const f16x8*)(ldsb + bo + roB[n][ks]);
#pragma unroll
            for (int m = 0; m < 4; m++)
#pragma unroll
                for (int n = 0; n < 2; n++)
                    acc[m][n] = __builtin_amdgcn_mfma_f32_16x16x32_f16(af[m], bf[n], acc[m][n], 0, 0, 0);
        }
        __syncthreads();
        if (t + 2 < NT) G2STAGE(t + 2, t & 1);
    }

#pragma unroll
    for (int n = 0; n < 2; n++) {
        int colg = cb + wn * 32 + n * 16 + fr;
        float bias = (kz == 0) ? b2[e * D_ + colg] : 0.f;
#pragma unroll
        for (int m = 0; m < 4; m++) {
#pragma unroll
            for (int r2 = 0; r2 < 4; r2++) {
                int j = rb + wm * 64 + m * 16 + qh * 4 + r2;
                if (j < cnt) {
                    int id = list[e * N_TOK + j];
                    float wgt = wslot[id];
                    float v = (acc[m][n][r2] + bias) * wgt;
                    atomicAdd(&out[(size_t)(id >> 1) * D_ + colg], v);
                }
            }
        }
    }
}

extern "C" void kernel_launch(void* const* d_in, const int* in_sizes, int n_in,
                              void* d_out, int out_size, void* d_ws, size_t ws_size,
                              hipStream_t stream) {
    const float* x = (const float*)d_in[0];
    const float* gate_w = (const float*)d_in[1];
    const float* gate_b = (const float*)d_in[2];
    const float* w1 = (const float*)d_in[3];
    const float* b1 = (const float*)d_in[4];
    const float* w2 = (const float*)d_in[5];
    const float* b2 = (const float*)d_in[6];
    float* out = (float*)d_out;

    char* ws = (char*)d_ws;
    int* counts = (int*)ws;                           // 32 B
    int* list = (int*)(ws + 1024);                    // 131072 B
    float* wslot = (float*)(ws + 132096);             // 32768 B
    f16* xg = (f16*)(ws + 196608);                    // 12582912 B
    f16* w1t = (f16*)(ws + 12779520);                 // 37748736 B
    f16* w2t = (f16*)(ws + 50528256);                 // 37748736 B
    f16* hbuf = (f16*)(ws + 88276992);                // 50331648 B

    hipMemsetAsync(counts, 0, 256, stream);
    hipMemsetAsync(out, 0, (size_t)out_size * sizeof(float), stream);

    router<<<64, 1024, 0, stream>>>(x, gate_w, gate_b, counts, list, wslot);
    pack_a<<<E_ * N_TOK / 4, 256, 0, stream>>>(x, counts, list, xg);
    cvt_w_both<<<dim3(576, 1, 16), 256, 0, stream>>>(w1, w2, w1t, w2t);
    gemm1<<<E_ * 2 * 64 * 24, 256, 0, stream>>>(xg, w1t, b1, counts, hbuf);
    gemm2<<<E_ * 2 * 32 * 6, 512, 0, stream>>>(hbuf, w2t, b2, counts, list, wslot, out);
}

// Round 17
// 256.287 us; speedup vs baseline: 1.3714x; 1.0568x over previous
//
#include <hip/hip_runtime.h>
#include <hip/hip_bf16.h>

#define D_ 768
#define E_ 8
#define H_ 3072
#define N_TOK 4096
#define BT 64
#define BK 64

typedef _Float16 f16;
typedef f16 f16x8 __attribute__((ext_vector_type(8)));
typedef float f32x4 __attribute__((ext_vector_type(4)));

__device__ __forceinline__ void gld16(const f16* g, f16* l) {
    __builtin_amdgcn_global_load_lds(
        (const __attribute__((address_space(1))) unsigned int*)g,
        (__attribute__((address_space(3))) unsigned int*)l, 16, 0, 0);
}

__device__ __forceinline__ int prefix_off(const int* counts, int e, int* cnt_out) {
    int off = 0, cnt = 0;
#pragma unroll
    for (int q = 0; q < E_; q++) {
        int cq = counts[q];
        if (q < e) off += cq;
        if (q == e) cnt = cq;
    }
    *cnt_out = cnt;
    return off;
}

// ---------------- combined weight convert+transpose+swizzle (w1 & w2 in one launch) ----------------
// fp32 [R][C] -> fp16 [C][R], output row swizzled in 16B chunks: chunk k at k^(row&7).
__global__ __launch_bounds__(256) void cvt_w_both(const float* __restrict__ w1,
                                                  const float* __restrict__ w2,
                                                  f16* __restrict__ w1t,
                                                  f16* __restrict__ w2t) {
    __shared__ f16 t[64][66];
    int z = blockIdx.z;
    const float* src; f16* dst; int R, C, xb, yb;
    int bx = blockIdx.x;
    if (z < E_) {
        src = w1 + (size_t)z * D_ * H_; dst = w1t + (size_t)z * D_ * H_;
        R = D_; C = H_; xb = bx % 48; yb = bx / 48;
    } else {
        src = w2 + (size_t)(z - E_) * H_ * D_; dst = w2t + (size_t)(z - E_) * H_ * D_;
        R = H_; C = D_; xb = bx % 12; yb = bx / 12;
    }
    int r0 = yb * 64, c0 = xb * 64;
    int tid = threadIdx.x;
    {
        int r = tid >> 4;
        int c = (tid & 15) * 4;
#pragma unroll
        for (int i = 0; i < 4; i++) {
            float4 v = *(const float4*)(src + (size_t)(r0 + r + i * 16) * C + (c0 + c));
            t[r + i * 16][c] = (f16)v.x;
            t[r + i * 16][c + 1] = (f16)v.y;
            t[r + i * 16][c + 2] = (f16)v.z;
            t[r + i * 16][c + 3] = (f16)v.w;
        }
    }
    __syncthreads();
    {
        int c = tid >> 3;
        int rr = (tid & 7) * 8;
        int ch = rr >> 3;
#pragma unroll
        for (int i = 0; i < 2; i++) {
            int cc = c + i * 32;
            int rowi = c0 + cc;
            f16x8 o;
#pragma unroll
            for (int j = 0; j < 8; j++) o[j] = t[rr + j][cc];
            *(f16x8*)(dst + (size_t)rowi * R + r0 + (((ch ^ rowi) & 7) << 3)) = o;
        }
    }
}

// ---------------- router: coalesced GEMV + LDS-aggregated atomics ----------------
__global__ __launch_bounds__(1024) void router(const float* __restrict__ x,
                                               const float* __restrict__ gw,
                                               const float* __restrict__ gb,
                                               int* __restrict__ counts,
                                               int* __restrict__ list,
                                               float* __restrict__ wslot) {
    __shared__ int lcount[E_];
    __shared__ int lbase[E_];
    __shared__ int te0[64], te1[64], ts0[64], ts1[64];
    __shared__ float tw0[64], tw1[64];

    int tid = threadIdx.x;
    int wv = tid >> 6, lane = tid & 63;
    int s = lane >> 3, eL = lane & 7;
    if (tid < E_) lcount[tid] = 0;
    __syncthreads();

    float biasL = gb[eL];

#pragma unroll 1
    for (int i = 0; i < 4; i++) {
        int lt = wv * 4 + i;
        int tok = blockIdx.x * 64 + lt;
        const float* xr = x + (size_t)tok * D_;
        float a = 0.f;
        const float* gwl = gw + lane;
#pragma unroll 8
        for (int j = 0; j < 96; j++)
            a = fmaf(xr[j * 8 + s], gwl[j * 64], a);
        a += __shfl_xor(a, 8, 64);
        a += __shfl_xor(a, 16, 64);
        a += __shfl_xor(a, 32, 64);
        float lg = a + biasL;
        float le[8];
#pragma unroll
        for (int q = 0; q < 8; q++) le[q] = __shfl(lg, q, 64);
        float v0 = -3.4e38f, v1 = -3.4e38f;
        int i0 = 0, i1 = 0;
#pragma unroll
        for (int q = 0; q < 8; q++) {
            float l = le[q];
            if (l > v0) { v1 = v0; i1 = i0; v0 = l; i0 = q; }
            else if (l > v1) { v1 = l; i1 = q; }
        }
        if (lane == 0) {
            float p1 = expf(v1 - v0);
            float ssum = 1.f + p1;
            int s0 = atomicAdd(&lcount[i0], 1);
            int s1 = atomicAdd(&lcount[i1], 1);
            te0[lt] = i0; ts0[lt] = s0; tw0[lt] = 1.f / ssum;
            te1[lt] = i1; ts1[lt] = s1; tw1[lt] = p1 / ssum;
        }
    }
    __syncthreads();
    if (tid < E_) lbase[tid] = atomicAdd(&counts[tid], lcount[tid]);
    __syncthreads();
    if (tid < 64) {
        int tok = blockIdx.x * 64 + tid;
        int e0 = te0[tid], e1 = te1[tid];
        list[e0 * N_TOK + lbase[e0] + ts0[tid]] = tok * 2;
        list[e1 * N_TOK + lbase[e1] + ts1[tid]] = tok * 2 + 1;
        wslot[tok * 2] = tw0[tid];
        wslot[tok * 2 + 1] = tw1[tid];
    }
}

// ---------------- pack A: gather token rows -> packed swizzled fp16 [8192][D] ----------------
__global__ __launch_bounds__(256) void pack_a(const float* __restrict__ x,
                                              const int* __restrict__ counts,
                                              const int* __restrict__ list,
                                              f16* __restrict__ xg) {
    int wv = threadIdx.x >> 6, lane = threadIdx.x & 63;
    int idx = blockIdx.x * 4 + wv;
    int e = idx >> 12, j = idx & (N_TOK - 1);
    int cnt;
    int off = prefix_off(counts, e, &cnt);
    if (j >= cnt) return;
    int id = list[idx];
    int row = off + j;
    const float* xr = x + (size_t)(id >> 1) * D_;
    f16* dst = xg + (size_t)row * D_;
    int r7 = row & 7;
#pragma unroll
    for (int c = 0; c < 3; c++) {
        int h = lane * 4 + c * 256;
        float4 v = *(const float4*)(xr + h);
        f16 o[4] = {(f16)v.x, (f16)v.y, (f16)v.z, (f16)v.w};
        int hs = (h & ~0x3F) | ((((h >> 3) ^ r7) & 7) << 3) | (h & 7);
        *(float2*)(dst + hs) = *(const float2*)o;
    }
}

// ---------------- GEMM1: h = gelu(xg @ w1 + b1), 128x128x64, 4 waves x 64x64, single-buffer ----------------
#define G1BM 128
#define G1BN 128
#define G1BK 64
__global__ __launch_bounds__(256, 3) void gemm1(const f16* __restrict__ xg,
                                                const f16* __restrict__ w1t,
                                                const float* __restrict__ b1,
                                                const int* __restrict__ counts,
                                                f16* __restrict__ hbuf) {
    int bid = blockIdx.x;
    int e = bid & 7;                 // expert -> XCD
    int r = bid >> 3;
    int xb12 = r % 12;               // fastest (2.35MB B-half L2-resident)
    int yb = (r / 12) % 32;
    int xh = r / (12 * 32);          // slowest
    int cnt;
    int off = prefix_off(counts, e, &cnt);
    int rb = yb * G1BM;
    if (rb >= cnt) return;
    int cb = (xh * 12 + xb12) * G1BN;

    __shared__ f16 lds[(G1BM + G1BN) * G1BK];   // 32 KB: A halfs [0,8192), B [8192,16384)
    char* ldsb = (char*)lds;

    int tid = threadIdx.x;
    int w = tid >> 6, l = tid & 63;
    int fr = l & 15, qh = l >> 4;
    int wm = w >> 1, wn = w & 1;     // 2x2 waves, each 64x64 output

    // staging: A has 1024 16B-chunks (128 rows x 8), B same; chunk c = j*256 + w*64 + l
    const f16* gpA[4]; const f16* gpB[4];
    f16* lbA[4]; f16* lbB[4];
#pragma unroll
    for (int j = 0; j < 4; j++) {
        int c = j * 256 + w * 64 + l;
        int rowi = c >> 3, q = c & 7;
        int ag = off + rb + rowi; if (ag > 8191) ag = 8191;
        gpA[j] = xg + (size_t)ag * D_ + q * 8;
        lbA[j] = lds + j * 2048 + w * 512;       // wave-uniform base (halfs)
        gpB[j] = w1t + (size_t)e * H_ * D_ + (size_t)(cb + rowi) * D_ + q * 8;
        lbB[j] = lds + 8192 + j * 2048 + w * 512;
    }

    // ds_read offsets (XOR-8 rows; A param = global packed row, B local row, cb%8==0)
    int roA[4][2], roB[4][2];
#pragma unroll
    for (int m = 0; m < 4; m++)
#pragma unroll
        for (int ks = 0; ks < 2; ks++) {
            int rA = wm * 64 + m * 16 + fr;
            int g = off + rb + rA;
            roA[m][ks] = rA * 128 + ((((ks * 4 + qh) ^ g) & 7) << 4);
            int rB = wn * 64 + m * 16 + fr;
            roB[m][ks] = 16384 + rB * 128 + ((((ks * 4 + qh) ^ rB) & 7) << 4);
        }

    f32x4 acc[4][4] = {};
    const int NT = D_ / G1BK;   // 12
#pragma unroll 1
    for (int t = 0; t < NT; ++t) {
        int kk = t * G1BK;
#pragma unroll
        for (int j = 0; j < 4; j++) {
            gld16(gpA[j] + kk, lbA[j]);
            gld16(gpB[j] + kk, lbB[j]);
        }
        __syncthreads();
#pragma unroll
        for (int ks = 0; ks < 2; ks++) {
            f16x8 af[4], bf[4];
#pragma unroll
            for (int m = 0; m < 4; m++) af[m] = *(const f16x8*)(ldsb + roA[m][ks]);
#pragma unroll
            for (int n = 0; n < 4; n++) bf[n] = *(const f16x8*)(ldsb + roB[n][ks]);
#pragma unroll
            for (int m = 0; m < 4; m++)
#pragma unroll
                for (int n = 0; n < 4; n++)
                    acc[m][n] = __builtin_amdgcn_mfma_f32_16x16x32_f16(af[m], bf[n], acc[m][n], 0, 0, 0);
        }
        __syncthreads();
    }

#pragma unroll
    for (int n = 0; n < 4; n++) {
        int colg = cb + wn * 64 + n * 16 + fr;
        float bias = b1[e * H_ + colg];
#pragma unroll
        for (int m = 0; m < 4; m++) {
#pragma unroll
            for (int r2 = 0; r2 < 4; r2++) {
                int j = rb + wm * 64 + m * 16 + qh * 4 + r2;
                if (j < cnt) {
                    float v = acc[m][n][r2] + bias;
                    v = 0.5f * v * (1.f + erff(v * 0.70710678f));
                    int row = off + j;
                    int hs = (colg & ~0x3F) | ((((colg >> 3) ^ row) & 7) << 3) | (colg & 7);
                    hbuf[(size_t)row * H_ + hs] = (f16)v;
                }
            }
        }
    }
}

// ---------------- GEMM2 (R13-verified): 64x64, gld_lds, XCD-pinned, L2-blocked ----------------
#define KSPLIT 2
#define KCH (H_ / KSPLIT)
__global__ __launch_bounds__(256, 8) void gemm2(const f16* __restrict__ hbuf,
                                                const f16* __restrict__ w2t,
                                                const float* __restrict__ b2,
                                                const int* __restrict__ counts,
                                                const int* __restrict__ list,
                                                const float* __restrict__ wslot,
                                                float* __restrict__ out) {
    int bid = blockIdx.x;
    int e = bid & 7;
    int r = bid >> 3;
    int cb12 = r % 12;
    int yb = (r / 12) % 64;
    int kz = r / (12 * 64);
    int cnt;
    int off = prefix_off(counts, e, &cnt);
    int rb = yb * BT;
    if (rb >= cnt) return;
    int cb = cb12 * BT;
    int k0 = kz * KCH;

    __shared__ f16 lds[2 * BT * BK];
    char* ldsb = (char*)lds;

    int tid = threadIdx.x;
    int wv = tid >> 6, lane = tid & 63;
    int lr = lane >> 3, lc = lane & 7;

    int r0l = wv * 8 + lr;
    int r1l = 32 + wv * 8 + lr;
    int ag0 = off + rb + r0l; if (ag0 > 8191) ag0 = 8191;
    int ag1 = off + rb + r1l; if (ag1 > 8191) ag1 = 8191;
    const f16* ap0 = hbuf + (size_t)ag0 * H_ + k0 + lc * 8;
    const f16* ap1 = hbuf + (size_t)ag1 * H_ + k0 + lc * 8;
    const f16* wb = w2t + (size_t)e * D_ * H_;
    const f16* bp0 = wb + (size_t)(cb + r0l) * H_ + k0 + lc * 8;
    const f16* bp1 = wb + (size_t)(cb + r1l) * H_ + k0 + lc * 8;
    f16* la0 = lds + wv * 512;
    f16* la1 = lds + 2048 + wv * 512;
    f16* lb0 = lds + 4096 + wv * 512;
    f16* lb1 = lds + 6144 + wv * 512;

    int wr = (wv >> 1) * 32, wc = (wv & 1) * 32;
    int fr = lane & 15, qh = lane >> 4;
    int koff = (off + rb) & 7;

    int roA[2][2], roB[2][2];
#pragma unroll
    for (int m = 0; m < 2; m++)
#pragma unroll
        for (int ks = 0; ks < 2; ks++) {
            int row = wr + m * 16 + fr;
            roA[m][ks] = row * 128 + ((((ks * 4 + qh) ^ (koff + row)) & 7) << 4);
            int rwb = wc + m * 16 + fr;
            roB[m][ks] = 8192 + rwb * 128 + ((((ks * 4 + qh) ^ rwb) & 7) << 4);
        }

    f32x4 acc[2][2] = {};
    const int NT = KCH / BK;  // 24
#pragma unroll 1
    for (int t = 0; t < NT; ++t) {
        int kk = t * BK;
        gld16(ap0 + kk, la0);
        gld16(ap1 + kk, la1);
        gld16(bp0 + kk, lb0);
        gld16(bp1 + kk, lb1);
        __syncthreads();
#pragma unroll
        for (int ks = 0; ks < 2; ks++) {
            f16x8 a0 = *(const f16x8*)(ldsb + roA[0][ks]);
            f16x8 a1 = *(const f16x8*)(ldsb + roA[1][ks]);
            f16x8 b0 = *(const f16x8*)(ldsb + roB[0][ks]);
            f16x8 b1v = *(const f16x8*)(ldsb + roB[1][ks]);
            acc[0][0] = __builtin_amdgcn_mfma_f32_16x16x32_f16(a0, b0, acc[0][0], 0, 0, 0);
            acc[0][1] = __builtin_amdgcn_mfma_f32_16x16x32_f16(a0, b1v, acc[0][1], 0, 0, 0);
            acc[1][0] = __builtin_amdgcn_mfma_f32_16x16x32_f16(a1, b0, acc[1][0], 0, 0, 0);
            acc[1][1] = __builtin_amdgcn_mfma_f32_16x16x32_f16(a1, b1v, acc[1][1], 0, 0, 0);
        }
        __syncthreads();
    }

#pragma unroll
    for (int n = 0; n < 2; n++) {
        int colg = cb + wc + n * 16 + fr;
        float bias = (kz == 0) ? b2[e * D_ + colg] : 0.f;
#pragma unroll
        for (int m = 0; m < 2; m++) {
#pragma unroll
            for (int r2 = 0; r2 < 4; r2++) {
                int j = rb + wr + m * 16 + qh * 4 + r2;
                if (j < cnt) {
                    int id = list[e * N_TOK + j];
                    float w = wslot[id];
                    float v = (acc[m][n][r2] + bias) * w;
                    atomicAdd(&out[(size_t)(id >> 1) * D_ + colg], v);
                }
            }
        }
    }
}

extern "C" void kernel_launch(void* const* d_in, const int* in_sizes, int n_in,
                              void* d_out, int out_size, void* d_ws, size_t ws_size,
                              hipStream_t stream) {
    const float* x = (const float*)d_in[0];
    const float* gate_w = (const float*)d_in[1];
    const float* gate_b = (const float*)d_in[2];
    const float* w1 = (const float*)d_in[3];
    const float* b1 = (const float*)d_in[4];
    const float* w2 = (const float*)d_in[5];
    const float* b2 = (const float*)d_in[6];
    float* out = (float*)d_out;

    char* ws = (char*)d_ws;
    int* counts = (int*)ws;                           // 32 B
    int* list = (int*)(ws + 1024);                    // 131072 B
    float* wslot = (float*)(ws + 132096);             // 32768 B
    f16* xg = (f16*)(ws + 196608);                    // 12582912 B
    f16* w1t = (f16*)(ws + 12779520);                 // 37748736 B
    f16* w2t = (f16*)(ws + 50528256);                 // 37748736 B
    f16* hbuf = (f16*)(ws + 88276992);                // 50331648 B

    hipMemsetAsync(counts, 0, 256, stream);
    hipMemsetAsync(out, 0, (size_t)out_size * sizeof(float), stream);

    router<<<64, 1024, 0, stream>>>(x, gate_w, gate_b, counts, list, wslot);
    pack_a<<<E_ * N_TOK / 4, 256, 0, stream>>>(x, counts, list, xg);
    cvt_w_both<<<dim3(576, 1, 16), 256, 0, stream>>>(w1, w2, w1t, w2t);
    gemm1<<<E_ * 2 * 32 * 12, 256, 0, stream>>>(xg, w1t, b1, counts, hbuf);
    gemm2<<<E_ * 2 * 64 * 12, 256, 0, stream>>>(hbuf, w2t, b2, counts, list, wslot, out);
}

// Round 18
// 240.940 us; speedup vs baseline: 1.4588x; 1.0637x over previous
//
#include <hip/hip_runtime.h>
#include <hip/hip_bf16.h>

#define D_ 768
#define E_ 8
#define H_ 3072
#define N_TOK 4096
#define BT 64
#define BK 64

typedef _Float16 f16;
typedef f16 f16x8 __attribute__((ext_vector_type(8)));
typedef float f32x4 __attribute__((ext_vector_type(4)));

__device__ __forceinline__ void gld16(const f16* g, f16* l) {
    __builtin_amdgcn_global_load_lds(
        (const __attribute__((address_space(1))) unsigned int*)g,
        (__attribute__((address_space(3))) unsigned int*)l, 16, 0, 0);
}

__device__ __forceinline__ int prefix_off(const int* counts, int e, int* cnt_out) {
    int off = 0, cnt = 0;
#pragma unroll
    for (int q = 0; q < E_; q++) {
        int cq = counts[q];
        if (q < e) off += cq;
        if (q == e) cnt = cq;
    }
    *cnt_out = cnt;
    return off;
}

// ---------------- router: coalesced GEMV + LDS-aggregated atomics ----------------
__global__ __launch_bounds__(1024) void router(const float* __restrict__ x,
                                               const float* __restrict__ gw,
                                               const float* __restrict__ gb,
                                               int* __restrict__ counts,
                                               int* __restrict__ list,
                                               float* __restrict__ wslot) {
    __shared__ int lcount[E_];
    __shared__ int lbase[E_];
    __shared__ int te0[64], te1[64], ts0[64], ts1[64];
    __shared__ float tw0[64], tw1[64];

    int tid = threadIdx.x;
    int wv = tid >> 6, lane = tid & 63;
    int s = lane >> 3, eL = lane & 7;
    if (tid < E_) lcount[tid] = 0;
    __syncthreads();

    float biasL = gb[eL];

#pragma unroll 1
    for (int i = 0; i < 4; i++) {
        int lt = wv * 4 + i;
        int tok = blockIdx.x * 64 + lt;
        const float* xr = x + (size_t)tok * D_;
        float a = 0.f;
        const float* gwl = gw + lane;
#pragma unroll 8
        for (int j = 0; j < 96; j++)
            a = fmaf(xr[j * 8 + s], gwl[j * 64], a);
        a += __shfl_xor(a, 8, 64);
        a += __shfl_xor(a, 16, 64);
        a += __shfl_xor(a, 32, 64);
        float lg = a + biasL;
        float le[8];
#pragma unroll
        for (int q = 0; q < 8; q++) le[q] = __shfl(lg, q, 64);
        float v0 = -3.4e38f, v1 = -3.4e38f;
        int i0 = 0, i1 = 0;
#pragma unroll
        for (int q = 0; q < 8; q++) {
            float l = le[q];
            if (l > v0) { v1 = v0; i1 = i0; v0 = l; i0 = q; }
            else if (l > v1) { v1 = l; i1 = q; }
        }
        if (lane == 0) {
            float p1 = expf(v1 - v0);
            float ssum = 1.f + p1;
            int s0 = atomicAdd(&lcount[i0], 1);
            int s1 = atomicAdd(&lcount[i1], 1);
            te0[lt] = i0; ts0[lt] = s0; tw0[lt] = 1.f / ssum;
            te1[lt] = i1; ts1[lt] = s1; tw1[lt] = p1 / ssum;
        }
    }
    __syncthreads();
    if (tid < E_) lbase[tid] = atomicAdd(&counts[tid], lcount[tid]);
    __syncthreads();
    if (tid < 64) {
        int tok = blockIdx.x * 64 + tid;
        int e0 = te0[tid], e1 = te1[tid];
        list[e0 * N_TOK + lbase[e0] + ts0[tid]] = tok * 2;
        list[e1 * N_TOK + lbase[e1] + ts1[tid]] = tok * 2 + 1;
        wslot[tok * 2] = tw0[tid];
        wslot[tok * 2 + 1] = tw1[tid];
    }
}

// ---------------- prep: fused weight-convert (blocks 0..9215) + pack_a (blocks 9216..17407) ----------------
// cvt: fp32 [R][C] -> fp16 [C][R], row swizzled in 16B chunks: chunk k at k^(row&7).
// pack: gather token rows -> packed swizzled fp16 [8192][D].
#define CVT_BLKS 9216   // 576 * 16
__global__ __launch_bounds__(256) void prep(const float* __restrict__ w1,
                                            const float* __restrict__ w2,
                                            f16* __restrict__ w1t,
                                            f16* __restrict__ w2t,
                                            const float* __restrict__ x,
                                            const int* __restrict__ counts,
                                            const int* __restrict__ list,
                                            f16* __restrict__ xg) {
    __shared__ f16 t[64][66];
    int bid = blockIdx.x;
    int tid = threadIdx.x;

    if (bid < CVT_BLKS) {
        int z = bid / 576;
        int bx = bid % 576;
        const float* src; f16* dst; int R, C, xb, yb;
        if (z < E_) {
            src = w1 + (size_t)z * D_ * H_; dst = w1t + (size_t)z * D_ * H_;
            R = D_; C = H_; xb = bx % 48; yb = bx / 48;
        } else {
            src = w2 + (size_t)(z - E_) * H_ * D_; dst = w2t + (size_t)(z - E_) * H_ * D_;
            R = H_; C = D_; xb = bx % 12; yb = bx / 12;
        }
        int r0 = yb * 64, c0 = xb * 64;
        {
            int r = tid >> 4;
            int c = (tid & 15) * 4;
#pragma unroll
            for (int i = 0; i < 4; i++) {
                float4 v = *(const float4*)(src + (size_t)(r0 + r + i * 16) * C + (c0 + c));
                t[r + i * 16][c] = (f16)v.x;
                t[r + i * 16][c + 1] = (f16)v.y;
                t[r + i * 16][c + 2] = (f16)v.z;
                t[r + i * 16][c + 3] = (f16)v.w;
            }
        }
        __syncthreads();
        {
            int c = tid >> 3;
            int rr = (tid & 7) * 8;
            int ch = rr >> 3;
#pragma unroll
            for (int i = 0; i < 2; i++) {
                int cc = c + i * 32;
                int rowi = c0 + cc;
                f16x8 o;
#pragma unroll
                for (int j = 0; j < 8; j++) o[j] = t[rr + j][cc];
                *(f16x8*)(dst + (size_t)rowi * R + r0 + (((ch ^ rowi) & 7) << 3)) = o;
            }
        }
    } else {
        int wv = tid >> 6, lane = tid & 63;
        int idx = (bid - CVT_BLKS) * 4 + wv;          // e*N_TOK + j
        int e = idx >> 12, j = idx & (N_TOK - 1);
        int cnt;
        int off = prefix_off(counts, e, &cnt);
        if (j >= cnt) return;
        int id = list[idx];
        int row = off + j;
        const float* xr = x + (size_t)(id >> 1) * D_;
        f16* dst = xg + (size_t)row * D_;
        int r7 = row & 7;
#pragma unroll
        for (int c = 0; c < 3; c++) {
            int h = lane * 4 + c * 256;
            float4 v = *(const float4*)(xr + h);
            f16 o[4] = {(f16)v.x, (f16)v.y, (f16)v.z, (f16)v.w};
            int hs = (h & ~0x3F) | ((((h >> 3) ^ r7) & 7) << 3) | (h & 7);
            *(float2*)(dst + hs) = *(const float2*)o;
        }
    }
}

// ---------------- GEMM1: h = gelu(xg @ w1 + b1), 64x64, gld_lds, XCD-pinned, L2-blocked ----------------
__global__ __launch_bounds__(256, 8) void gemm1(const f16* __restrict__ xg,
                                                const f16* __restrict__ w1t,
                                                const float* __restrict__ b1,
                                                const int* __restrict__ counts,
                                                f16* __restrict__ hbuf) {
    int bid = blockIdx.x;
    int e = bid & 7;
    int r = bid >> 3;
    int xb24 = r % 24;
    int yb = (r / 24) % 64;
    int xh = r / (24 * 64);
    int cnt;
    int off = prefix_off(counts, e, &cnt);
    int rb = yb * BT;
    if (rb >= cnt) return;
    int cb = (xh * 24 + xb24) * BT;

    __shared__ f16 lds[2 * BT * BK];
    char* ldsb = (char*)lds;

    int tid = threadIdx.x;
    int wv = tid >> 6, lane = tid & 63;
    int lr = lane >> 3, lc = lane & 7;

    int r0l = wv * 8 + lr;
    int r1l = 32 + wv * 8 + lr;
    int ag0 = off + rb + r0l; if (ag0 > 8191) ag0 = 8191;
    int ag1 = off + rb + r1l; if (ag1 > 8191) ag1 = 8191;
    const f16* ap0 = xg + (size_t)ag0 * D_ + lc * 8;
    const f16* ap1 = xg + (size_t)ag1 * D_ + lc * 8;
    const f16* wb = w1t + (size_t)e * H_ * D_;
    const f16* bp0 = wb + (size_t)(cb + r0l) * D_ + lc * 8;
    const f16* bp1 = wb + (size_t)(cb + r1l) * D_ + lc * 8;
    f16* la0 = lds + wv * 512;
    f16* la1 = lds + 2048 + wv * 512;
    f16* lb0 = lds + 4096 + wv * 512;
    f16* lb1 = lds + 6144 + wv * 512;

    int wr = (wv >> 1) * 32, wc = (wv & 1) * 32;
    int fr = lane & 15, qh = lane >> 4;
    int koff = (off + rb) & 7;

    int roA[2][2], roB[2][2];
#pragma unroll
    for (int m = 0; m < 2; m++)
#pragma unroll
        for (int ks = 0; ks < 2; ks++) {
            int row = wr + m * 16 + fr;
            roA[m][ks] = row * 128 + ((((ks * 4 + qh) ^ (koff + row)) & 7) << 4);
            int rwb = wc + m * 16 + fr;
            roB[m][ks] = 8192 + rwb * 128 + ((((ks * 4 + qh) ^ rwb) & 7) << 4);
        }

    f32x4 acc[2][2] = {};
    const int NT = D_ / BK;  // 12
#pragma unroll 1
    for (int t = 0; t < NT; ++t) {
        int kk = t * BK;
        gld16(ap0 + kk, la0);
        gld16(ap1 + kk, la1);
        gld16(bp0 + kk, lb0);
        gld16(bp1 + kk, lb1);
        __syncthreads();
#pragma unroll
        for (int ks = 0; ks < 2; ks++) {
            f16x8 a0 = *(const f16x8*)(ldsb + roA[0][ks]);
            f16x8 a1 = *(const f16x8*)(ldsb + roA[1][ks]);
            f16x8 b0 = *(const f16x8*)(ldsb + roB[0][ks]);
            f16x8 b1v = *(const f16x8*)(ldsb + roB[1][ks]);
            acc[0][0] = __builtin_amdgcn_mfma_f32_16x16x32_f16(a0, b0, acc[0][0], 0, 0, 0);
            acc[0][1] = __builtin_amdgcn_mfma_f32_16x16x32_f16(a0, b1v, acc[0][1], 0, 0, 0);
            acc[1][0] = __builtin_amdgcn_mfma_f32_16x16x32_f16(a1, b0, acc[1][0], 0, 0, 0);
            acc[1][1] = __builtin_amdgcn_mfma_f32_16x16x32_f16(a1, b1v, acc[1][1], 0, 0, 0);
        }
        __syncthreads();
    }

#pragma unroll
    for (int n = 0; n < 2; n++) {
        int colg = cb + wc + n * 16 + fr;
        float bias = b1[e * H_ + colg];
#pragma unroll
        for (int m = 0; m < 2; m++) {
#pragma unroll
            for (int r2 = 0; r2 < 4; r2++) {
                int j = rb + wr + m * 16 + qh * 4 + r2;
                if (j < cnt) {
                    float v = acc[m][n][r2] + bias;
                    v = 0.5f * v * (1.f + erff(v * 0.70710678f));
                    int row = off + j;
                    int hs = (colg & ~0x3F) | ((((colg >> 3) ^ row) & 7) << 3) | (colg & 7);
                    hbuf[(size_t)row * H_ + hs] = (f16)v;
                }
            }
        }
    }
}

// ---------------- GEMM2: y = (hbuf @ w2 + b2) * wslot, scatter-add; KSPLIT=1 ----------------
__global__ __launch_bounds__(256, 8) void gemm2(const f16* __restrict__ hbuf,
                                                const f16* __restrict__ w2t,
                                                const float* __restrict__ b2,
                                                const int* __restrict__ counts,
                                                const int* __restrict__ list,
                                                const float* __restrict__ wslot,
                                                float* __restrict__ out) {
    int bid = blockIdx.x;
    int e = bid & 7;
    int r = bid >> 3;
    int cb12 = r % 12;
    int yb = r / 12;                 // 0..63
    int cnt;
    int off = prefix_off(counts, e, &cnt);
    int rb = yb * BT;
    if (rb >= cnt) return;
    int cb = cb12 * BT;

    __shared__ f16 lds[2 * BT * BK];
    char* ldsb = (char*)lds;

    int tid = threadIdx.x;
    int wv = tid >> 6, lane = tid & 63;
    int lr = lane >> 3, lc = lane & 7;

    int r0l = wv * 8 + lr;
    int r1l = 32 + wv * 8 + lr;
    int ag0 = off + rb + r0l; if (ag0 > 8191) ag0 = 8191;
    int ag1 = off + rb + r1l; if (ag1 > 8191) ag1 = 8191;
    const f16* ap0 = hbuf + (size_t)ag0 * H_ + lc * 8;
    const f16* ap1 = hbuf + (size_t)ag1 * H_ + lc * 8;
    const f16* wb = w2t + (size_t)e * D_ * H_;
    const f16* bp0 = wb + (size_t)(cb + r0l) * H_ + lc * 8;
    const f16* bp1 = wb + (size_t)(cb + r1l) * H_ + lc * 8;
    f16* la0 = lds + wv * 512;
    f16* la1 = lds + 2048 + wv * 512;
    f16* lb0 = lds + 4096 + wv * 512;
    f16* lb1 = lds + 6144 + wv * 512;

    int wr = (wv >> 1) * 32, wc = (wv & 1) * 32;
    int fr = lane & 15, qh = lane >> 4;
    int koff = (off + rb) & 7;

    int roA[2][2], roB[2][2];
#pragma unroll
    for (int m = 0; m < 2; m++)
#pragma unroll
        for (int ks = 0; ks < 2; ks++) {
            int row = wr + m * 16 + fr;
            roA[m][ks] = row * 128 + ((((ks * 4 + qh) ^ (koff + row)) & 7) << 4);
            int rwb = wc + m * 16 + fr;
            roB[m][ks] = 8192 + rwb * 128 + ((((ks * 4 + qh) ^ rwb) & 7) << 4);
        }

    f32x4 acc[2][2] = {};
    const int NT = H_ / BK;  // 48
#pragma unroll 1
    for (int t = 0; t < NT; ++t) {
        int kk = t * BK;
        gld16(ap0 + kk, la0);
        gld16(ap1 + kk, la1);
        gld16(bp0 + kk, lb0);
        gld16(bp1 + kk, lb1);
        __syncthreads();
#pragma unroll
        for (int ks = 0; ks < 2; ks++) {
            f16x8 a0 = *(const f16x8*)(ldsb + roA[0][ks]);
            f16x8 a1 = *(const f16x8*)(ldsb + roA[1][ks]);
            f16x8 b0 = *(const f16x8*)(ldsb + roB[0][ks]);
            f16x8 b1v = *(const f16x8*)(ldsb + roB[1][ks]);
            acc[0][0] = __builtin_amdgcn_mfma_f32_16x16x32_f16(a0, b0, acc[0][0], 0, 0, 0);
            acc[0][1] = __builtin_amdgcn_mfma_f32_16x16x32_f16(a0, b1v, acc[0][1], 0, 0, 0);
            acc[1][0] = __builtin_amdgcn_mfma_f32_16x16x32_f16(a1, b0, acc[1][0], 0, 0, 0);
            acc[1][1] = __builtin_amdgcn_mfma_f32_16x16x32_f16(a1, b1v, acc[1][1], 0, 0, 0);
        }
        __syncthreads();
    }

#pragma unroll
    for (int n = 0; n < 2; n++) {
        int colg = cb + wc + n * 16 + fr;
        float bias = b2[e * D_ + colg];
#pragma unroll
        for (int m = 0; m < 2; m++) {
#pragma unroll
            for (int r2 = 0; r2 < 4; r2++) {
                int j = rb + wr + m * 16 + qh * 4 + r2;
                if (j < cnt) {
                    int id = list[e * N_TOK + j];
                    float w = wslot[id];
                    float v = (acc[m][n][r2] + bias) * w;
                    atomicAdd(&out[(size_t)(id >> 1) * D_ + colg], v);
                }
            }
        }
    }
}

extern "C" void kernel_launch(void* const* d_in, const int* in_sizes, int n_in,
                              void* d_out, int out_size, void* d_ws, size_t ws_size,
                              hipStream_t stream) {
    const float* x = (const float*)d_in[0];
    const float* gate_w = (const float*)d_in[1];
    const float* gate_b = (const float*)d_in[2];
    const float* w1 = (const float*)d_in[3];
    const float* b1 = (const float*)d_in[4];
    const float* w2 = (const float*)d_in[5];
    const float* b2 = (const float*)d_in[6];
    float* out = (float*)d_out;

    char* ws = (char*)d_ws;
    int* counts = (int*)ws;                           // 32 B
    int* list = (int*)(ws + 1024);                    // 131072 B
    float* wslot = (float*)(ws + 132096);             // 32768 B
    f16* xg = (f16*)(ws + 196608);                    // 12582912 B
    f16* w1t = (f16*)(ws + 12779520);                 // 37748736 B
    f16* w2t = (f16*)(ws + 50528256);                 // 37748736 B
    f16* hbuf = (f16*)(ws + 88276992);                // 50331648 B

    hipMemsetAsync(counts, 0, 256, stream);
    hipMemsetAsync(out, 0, (size_t)out_size * sizeof(float), stream);

    router<<<64, 1024, 0, stream>>>(x, gate_w, gate_b, counts, list, wslot);
    prep<<<CVT_BLKS + E_ * N_TOK / 4, 256, 0, stream>>>(w1, w2, w1t, w2t, x, counts, list, xg);
    gemm1<<<E_ * 2 * 64 * 24, 256, 0, stream>>>(xg, w1t, b1, counts, hbuf);
    gemm2<<<E_ * 64 * 12, 256, 0, stream>>>(hbuf, w2t, b2, counts, list, wslot, out);
}